// Round 11
// baseline (64.214 us; speedup 1.0000x reference)
//
#include <hip/hip_runtime.h>
#include <hip/hip_bf16.h>
#include <math.h>

#define DN     0.35355339059327373f   /* sqrt(1/8) */
#define RATIO  0.08838834764831845f   /* 1/sqrt(128) */
#define TEMP   0.125f
#define KLS    8.0f                   /* fixed key stabilizer: cancels exactly */

typedef short s16x8 __attribute__((ext_vector_type(8)));
typedef float f32x4 __attribute__((ext_vector_type(4)));

static __device__ __forceinline__ ushort f2bf(float f) {
    __hip_bfloat16 h = __float2bfloat16(f);
    return *reinterpret_cast<ushort*>(&h);
}
static __device__ __forceinline__ float bf2f(ushort u) {
    __hip_bfloat16 h = *reinterpret_cast<__hip_bfloat16*>(&u);
    return __bfloat162float(h);
}
static __device__ __forceinline__ s16x8 pack8(const ushort* u) {
    union { s16x8 v; ushort u[8]; } P;
#pragma unroll
    for (int i = 0; i < 8; ++i) P.u[i] = u[i];
    return P.v;
}
static __device__ __forceinline__ float load8_split(const float* p, s16x8& ho, s16x8& lo) {
    f32x4 a = *(const f32x4*)p;
    f32x4 b = *(const f32x4*)(p + 4);
    float v[8] = {a.x, a.y, a.z, a.w, b.x, b.y, b.z, b.w};
    ushort hu[8], lu[8];
    float ss = 0.f;
#pragma unroll
    for (int i = 0; i < 8; ++i) {
        ss += v[i] * v[i];
        hu[i] = f2bf(v[i]);
        lu[i] = f2bf(v[i] - bf2f(hu[i]));
    }
    ho = pack8(hu); lo = pack8(lu);
    return ss;
}

#define MFMA(a, b, c) __builtin_amdgcn_mfma_f32_16x16x32_bf16(a, b, c, 0, 0, 0)

// Device-wide barrier. Pollers use RELAXED atomic loads (agent scope -> MALL,
// no cache invalidate per poll — round 8's 15 GB FETCH storm came from
// acquire-per-poll). One ACQUIRE after the flag flips orders subsequent reads.
static __device__ __forceinline__ void grid_sync(unsigned int* cnt, unsigned int* flag) {
    __syncthreads();
    if (threadIdx.x == 0) {
        unsigned int prev = __hip_atomic_fetch_add(cnt, 1u, __ATOMIC_ACQ_REL,
                                                   __HIP_MEMORY_SCOPE_AGENT);
        if (prev == gridDim.x - 1u) {
            __hip_atomic_store(flag, 1u, __ATOMIC_RELEASE, __HIP_MEMORY_SCOPE_AGENT);
        } else {
            while (__hip_atomic_load(flag, __ATOMIC_RELAXED,
                                     __HIP_MEMORY_SCOPE_AGENT) == 0u)
                __builtin_amdgcn_s_sleep(8);
            (void)__hip_atomic_load(flag, __ATOMIC_ACQUIRE, __HIP_MEMORY_SCOPE_AGENT);
        }
    }
    __syncthreads();
}

// ===== fused: feat(q+k) -> kv reduce -> main. 512 blocks x 256 thr, 2/CU =====
// Block b: head h = b&7 (XCD-aligned), 16-row tile t0 = (b>>3)*16.
__global__ __launch_bounds__(256, 2) void fused_kernel(
    const float* __restrict__ qin, const float* __restrict__ kin,
    const float* __restrict__ vin, const float* __restrict__ proj,
    ushort* __restrict__ kh, ushort* __restrict__ kph,
    ushort* __restrict__ vT, ushort* __restrict__ kvT,
    float* __restrict__ ksum, float* __restrict__ pksum, float* __restrict__ pkv,
    unsigned int* __restrict__ bar, float* __restrict__ outp)
{
    __shared__ float p_lds[16][133];          // q' f32, persists to phase 3
    __shared__ float plss[16], qk1s[16], lns[16], pss[16];
    __shared__ float diag_q[16], diag_k[16], ad_lds[16];
    __shared__ float ad_part[4][16];
    __shared__ union {
        struct { float v_lds[16][65]; float kp_lds[16][133]; } p1;
        struct { float buf[2][128]; } p2;
        struct { float QKb[16][152]; float DPb[16][152]; ushort ATb[16][168]; } p3;
    } U;

    int tid = threadIdx.x, bid = blockIdx.x;
    int h = bid & 7, tI = bid >> 3, t0 = tI << 4;
    int w = tid >> 6, lane = tid & 63, l15 = lane & 15, lk = lane >> 4;
    int tl = tid >> 4, sub = tid & 15;

    // ================= phase 1: q + k features for own 16 rows =================
#pragma unroll
    for (int i = 0; i < 4; ++i) {
        int f = tid + 256 * i;
        int sl = f >> 6, e = f & 63;
        U.p1.v_lds[sl][e] = vin[((size_t)((t0 + sl) * 8 + h) << 6) + e];
    }
    s16x8 aqh[2], aql[2], akh[2], akl[2];
    float qq = 0.f, kk2 = 0.f;
#pragma unroll
    for (int kt = 0; kt < 2; ++kt) {
        size_t goff = ((size_t)((t0 + l15) * 8 + h) << 6) + kt * 32 + lk * 8;
        qq  += load8_split(qin + goff, aqh[kt], aql[kt]);
        kk2 += load8_split(kin + goff, akh[kt], akl[kt]);
        if (w == kt)
            *(s16x8*)(kh + goff) = akh[kt];
    }
    if (w == 0) {
        float s = qq; s += __shfl_xor(s, 16, 64); s += __shfl_xor(s, 32, 64);
        if (lk == 0) diag_q[l15] = 0.0625f * s;
    } else if (w == 1) {
        float s = kk2; s += __shfl_xor(s, 16, 64); s += __shfl_xor(s, 32, 64);
        if (lk == 0) diag_k[l15] = 0.0625f * s;
    }
    // dash GEMMs: split-bf16, each wave owns 16 proj cols
    f32x4 dq = {0,0,0,0}, dk = {0,0,0,0};
#pragma unroll
    for (int kt = 0; kt < 2; ++kt) {
        s16x8 bh, bl;
        load8_split(proj + ((w * 16 + l15) << 6) + kt * 32 + lk * 8, bh, bl);
        dq = MFMA(aqh[kt], bh, dq); dq = MFMA(aqh[kt], bl, dq); dq = MFMA(aql[kt], bh, dq);
        dk = MFMA(akh[kt], bh, dk); dk = MFMA(akh[kt], bl, dk); dk = MFMA(akl[kt], bh, dk);
    }
    // q per-row max|dash| across all 64 cols (both signs symmetric)
#pragma unroll
    for (int j = 0; j < 4; ++j) {
        float rm = fabsf(DN * dq[j]);
#pragma unroll
        for (int m = 1; m < 16; m <<= 1) rm = fmaxf(rm, __shfl_xor(rm, m, 16));
        if (l15 == 0) ad_part[w][lk * 4 + j] = rm;
    }
    __syncthreads();
    if (tid < 16) {
        float ad = fmaxf(fmaxf(ad_part[0][tid], ad_part[1][tid]),
                         fmaxf(ad_part[2][tid], ad_part[3][tid]));
        ad_lds[tid] = ad;
        plss[tid] = ad - diag_q[tid] + KLS;
    }
    __syncthreads();
#pragma unroll
    for (int j = 0; j < 4; ++j) {
        int row = lk * 4 + j, r = w * 16 + l15;
        float dashq = DN * dq[j], ad = ad_lds[row];
        p_lds[row][r]      = RATIO * __expf( dashq - ad);
        p_lds[row][64 + r] = RATIO * __expf(-dashq - ad);
        float dashk = DN * dk[j], cc = diag_k[row] + KLS;
        U.p1.kp_lds[row][r]      = RATIO * __expf( dashk - cc);
        U.p1.kp_lds[row][64 + r] = RATIO * __expf(-dashk - cc);
    }
    __syncthreads();
    // q' A-frags stay in registers (hi-only, plain-bf16 DP path per round 9)
    s16x8 aph[4];
#pragma unroll
    for (int kt = 0; kt < 4; ++kt) {
        ushort hu[8];
#pragma unroll
        for (int i = 0; i < 8; ++i) hu[i] = f2bf(p_lds[l15][kt * 32 + lk * 8 + i]);
        aph[kt] = pack8(hu);
    }
    // publish k' (hi-only, vectorized 16B stores)
    {
        int sl = tid >> 4, mc = (tid & 15) * 8;
        ushort tmp[8];
#pragma unroll
        for (int j = 0; j < 8; ++j) tmp[j] = f2bf(U.p1.kp_lds[sl][mc + j]);
        *(s16x8*)(kph + ((size_t)((t0 + sl) * 8 + h) << 7) + mc) = pack8(tmp);
    }
    if (tid < 128) {
        float s = 0.f;
#pragma unroll
        for (int sl = 0; sl < 16; ++sl) s += U.p1.kp_lds[sl][tid];
        pksum[(h * 64 + tI) * 128 + tid] = s;
    }
    // vT[h*64+d][t0+sidx] = v[t0+sidx][d]
#pragma unroll
    for (int j = 0; j < 4; ++j) {
        int o = tid + 256 * j;
        int d = o >> 4, sidx = o & 15;
        vT[((size_t)(h * 64 + d) << 10) + t0 + sidx] = f2bf(U.p1.v_lds[sidx][d]);
    }
    // kv partial GEMM (rank-16, zero-padded K to 32); pkv[h][chunk][d][m]
    {
        ushort tmp[8];
#pragma unroll
        for (int i = 0; i < 8; ++i) {
            int s = lk * 8 + i;
            tmp[i] = (s < 16) ? f2bf(U.p1.v_lds[s][w * 16 + l15]) : (ushort)0;
        }
        s16x8 bv = pack8(tmp);
        int d = w * 16 + l15;
        float* pkvb = pkv + ((size_t)(h * 64 + tI) << 13);
#pragma unroll
        for (int mt = 0; mt < 8; ++mt) {
            ushort ta[8];
#pragma unroll
            for (int i = 0; i < 8; ++i) {
                int s = lk * 8 + i;
                ta[i] = (s < 16) ? f2bf(U.p1.kp_lds[s][mt * 16 + l15]) : (ushort)0;
            }
            f32x4 acc = {0,0,0,0};
            acc = MFMA(pack8(ta), bv, acc);
            *(f32x4*)(pkvb + d * 128 + mt * 16 + lk * 4) = acc;
        }
    }

    grid_sync(bar + 0, bar + 64);

    // ================= phase 2: kv / ksum reduction =================
    {
        int h2 = bid & 7, d2 = bid >> 3;      // d2 in [0,64)
        int m = tid & 127, half = tid >> 7;
        float s = 0.f;
#pragma unroll
        for (int c = 0; c < 32; ++c) {
            int cc = half * 32 + c;
            s += pkv[((size_t)(h2 * 64 + cc) << 13) + d2 * 128 + m];
        }
        U.p2.buf[half][m] = s;
        __syncthreads();
        if (tid < 128)
            kvT[((size_t)(h2 * 64 + d2) << 7) + m] = f2bf(U.p2.buf[0][m] + U.p2.buf[1][m]);
        if (bid < 8 && tid < 128) {
            float ks = 0.f;
#pragma unroll
            for (int c = 0; c < 64; ++c) ks += pksum[(h2 * 64 + c) * 128 + tid];
            ksum[h2 * 128 + tid] = ks;
        }
    }

    grid_sync(bar + 128, bar + 192);

    // ================= phase 3: local window + combine (round-9 main) =========
    {
        const float* ksp = ksum + h * 128;
        float s = 0.f;
#pragma unroll
        for (int i = 0; i < 8; ++i) s += p_lds[tl][sub * 8 + i] * ksp[sub * 8 + i];
#pragma unroll
        for (int m = 1; m < 16; m <<= 1) s += __shfl_xor(s, m, 16);
        if (sub == 0) qk1s[tl] = s;
    }
    int dcol = w * 16 + l15;
    s16x8 bkv[4];
    {
        const ushort* kvTrow = kvT + ((size_t)(h * 64 + dcol) << 7);
#pragma unroll
        for (int kt = 0; kt < 4; ++kt)
            bkv[kt] = *(const s16x8*)(kvTrow + kt * 32 + lk * 8);
    }
    // QK & DP bf16 GEMMs over 9 window tiles
    for (int nt = w; nt < 9; nt += 4) {
        int srow = min(max(t0 - 64 + nt * 16 + l15, 0), 1023);
        size_t kbase = ((size_t)(srow * 8 + h)) << 6;
        size_t pbase = ((size_t)(srow * 8 + h)) << 7;
        s16x8 bkh[2], bph[4];
#pragma unroll
        for (int kt = 0; kt < 2; ++kt)
            bkh[kt] = *(const s16x8*)(kh + kbase + kt * 32 + lk * 8);
#pragma unroll
        for (int kt = 0; kt < 4; ++kt)
            bph[kt] = *(const s16x8*)(kph + pbase + kt * 32 + lk * 8);
        f32x4 aqk = {0,0,0,0}, adp = {0,0,0,0};
#pragma unroll
        for (int kt = 0; kt < 2; ++kt)
            aqk = MFMA(aqh[kt], bkh[kt], aqk);
#pragma unroll
        for (int kt = 0; kt < 4; ++kt)
            adp = MFMA(aph[kt], bph[kt], adp);
#pragma unroll
        for (int r = 0; r < 4; ++r) {
            int row = lk * 4 + r, cs = nt * 16 + l15;
            U.p3.QKb[row][cs] = TEMP * aqk[r];
            U.p3.DPb[row][cs] = adp[r];
        }
    }
    __syncthreads();

    // row stats -> log_norm, prime_scale
    int clo = max(tl, 64 - t0);
    int chi = min(tl + 128, 1088 - t0);
    float mx = -1e30f, dsum = 0.f;
#pragma unroll
    for (int kk = 0; kk < 9; ++kk) {
        int cs = sub + 16 * kk;
        if (cs >= clo && cs < chi) {
            mx = fmaxf(mx, U.p3.QKb[tl][cs]);
            dsum += U.p3.DPb[tl][cs];
        }
    }
#pragma unroll
    for (int m = 1; m < 16; m <<= 1) {
        mx = fmaxf(mx, __shfl_xor(mx, m, 16));
        dsum += __shfl_xor(dsum, m, 16);
    }
    float se = 0.f;
#pragma unroll
    for (int kk = 0; kk < 9; ++kk) {
        int cs = sub + 16 * kk;
        if (cs >= clo && cs < chi) se += __expf(U.p3.QKb[tl][cs] - mx);
    }
#pragma unroll
    for (int m = 1; m < 16; m <<= 1) se += __shfl_xor(se, m, 16);
    if (sub == 0) {
        float lse = mx + __logf(se);
        float lr = __logf(fmaxf(qk1s[tl] - dsum, 1e-24f)) + plss[tl];
        float mab = fmaxf(lse, lr);
        float ln = mab + log1pf(__expf(fminf(lse, lr) - mab));
        lns[tl] = ln;
        pss[tl] = __expf(plss[tl] - ln);
    }
    __syncthreads();

    // attn_local -> bf16 s-aligned buffer (zeros outside window)
    {
        float ln = lns[tl], ps = pss[tl];
#pragma unroll
        for (int kk = 0; kk < 10; ++kk) {
            int cs = sub + 16 * kk;
            float att = 0.f;
            if (kk < 9 && cs >= clo && cs < chi)
                att = __expf(U.p3.QKb[tl][cs] - ln) - U.p3.DPb[tl][cs] * ps;
            U.p3.ATb[tl][cs] = f2bf(att);
        }
    }
    __syncthreads();

    // out = attn_sb @ V + ps * (q' @ kv)
    f32x4 acc1 = {0,0,0,0}, acc2 = {0,0,0,0};
    const ushort* vTrow = vT + ((size_t)(h * 64 + dcol) << 10);
#pragma unroll
    for (int kt = 0; kt < 5; ++kt) {
        s16x8 a = *(const s16x8*)&U.p3.ATb[l15][kt * 32 + lk * 8];
        int sc = t0 - 64 + kt * 32 + lk * 8;
        sc = min(max(sc, 0), 1016);
        s16x8 b = *(const s16x8*)(vTrow + sc);
        acc1 = MFMA(a, b, acc1);
    }
#pragma unroll
    for (int kt = 0; kt < 4; ++kt)
        acc2 = MFMA(aph[kt], bkv[kt], acc2);
#pragma unroll
    for (int r = 0; r < 4; ++r) {
        int row = lk * 4 + r;
        float val = acc1[r] + pss[row] * acc2[r];
        outp[((size_t)((t0 + row) * 8 + h) << 6) + dcol] = val;
    }
}

extern "C" void kernel_launch(void* const* d_in, const int* in_sizes, int n_in,
                              void* d_out, int out_size, void* d_ws, size_t ws_size,
                              hipStream_t stream) {
    const float* q    = (const float*)d_in[0];
    const float* kk   = (const float*)d_in[1];
    const float* vv   = (const float*)d_in[2];
    const float* proj = (const float*)d_in[3];
    float* out = (float*)d_out;
    float* ws  = (float*)d_ws;

    unsigned int* bar = (unsigned int*)ws;       // 256 uints (1 KB), zeroed per call
    ushort* kh    = (ushort*)(ws + 256);         // 8192*64  bf16 (262144 f32)
    ushort* kph   = (ushort*)(ws + 262400);      // 8192*128 bf16 (524288 f32)
    ushort* vT    = (ushort*)(ws + 786688);      // 8*64*1024 bf16 (262144 f32)
    ushort* kvT   = (ushort*)(ws + 1048832);     // 8*64*128 bf16 (32768 f32)
    float*  ksum  = ws + 1081600;                // 1024
    float*  pksum = ws + 1082624;                // 8*64*128 f32 (65536)
    float*  pkv   = ws + 1148160;                // 8*64*64*128 f32 (4194304) -> ends 5342464

    hipMemsetAsync(bar, 0, 1024, stream);
    fused_kernel<<<512, 256, 0, stream>>>(q, kk, vv, proj, kh, kph, vT, kvT,
                                          ksum, pksum, pkv, bar, out);
}

// Round 12
// 25.067 us; speedup vs baseline: 2.5617x; 2.5617x over previous
//
#include <hip/hip_runtime.h>
#include <hip/hip_bf16.h>
#include <math.h>

#define DN     0.35355339059327373f   /* sqrt(1/8) */
#define RATIO  0.08838834764831845f   /* 1/sqrt(128) */
#define TEMP   0.125f
#define KLS    8.0f                   /* fixed key stabilizer: cancels exactly */

typedef short s16x8 __attribute__((ext_vector_type(8)));
typedef ushort u16x4 __attribute__((ext_vector_type(4)));
typedef float f32x4 __attribute__((ext_vector_type(4)));

static __device__ __forceinline__ ushort f2bf(float f) {
    __hip_bfloat16 h = __float2bfloat16(f);
    return *reinterpret_cast<ushort*>(&h);
}
static __device__ __forceinline__ float bf2f(ushort u) {
    __hip_bfloat16 h = *reinterpret_cast<__hip_bfloat16*>(&u);
    return __bfloat162float(h);
}
static __device__ __forceinline__ s16x8 pack8(const ushort* u) {
    union { s16x8 v; ushort u[8]; } P;
#pragma unroll
    for (int i = 0; i < 8; ++i) P.u[i] = u[i];
    return P.v;
}
static __device__ __forceinline__ float load8_split(const float* p, s16x8& ho, s16x8& lo) {
    f32x4 a = *(const f32x4*)p;
    f32x4 b = *(const f32x4*)(p + 4);
    float v[8] = {a.x, a.y, a.z, a.w, b.x, b.y, b.z, b.w};
    ushort hu[8], lu[8];
    float ss = 0.f;
#pragma unroll
    for (int i = 0; i < 8; ++i) {
        ss += v[i] * v[i];
        hu[i] = f2bf(v[i]);
        lu[i] = f2bf(v[i] - bf2f(hu[i]));
    }
    ho = pack8(hu); lo = pack8(lu);
    return ss;
}

#define MFMA(a, b, c) __builtin_amdgcn_mfma_f32_16x16x32_bf16(a, b, c, 0, 0, 0)

// ============ feat kernel: 512 blocks, h = blockIdx&7 (XCD-aligned) ============
// rest = blockIdx>>3: [0,32) = k-side chunks, [32,64) = q-side chunks (32 rows each)
// Publishes hi-only bf16 (qh/qph/kh/kph); dash GEMM split-bf16 for accuracy.
__global__ __launch_bounds__(256) void feat_kernel(const float* __restrict__ qin,
    const float* __restrict__ kin, const float* __restrict__ vin,
    const float* __restrict__ proj,
    ushort* __restrict__ qh, ushort* __restrict__ qph, float* __restrict__ qls,
    ushort* __restrict__ kh, ushort* __restrict__ kph,
    ushort* __restrict__ vT, ushort* __restrict__ pkv, float* __restrict__ pksum)
{
    __shared__ float v_lds[32][65];
    __shared__ float p_lds[32][133];
    __shared__ float diag_lds[32];
    __shared__ float ad_part[4][32];
    __shared__ float ad_lds[32];
    int tid = threadIdx.x;
    int bid = blockIdx.x;
    int h = bid & 7, rest = bid >> 3;
    int isq = rest >> 5;
    int c = rest & 31, s0 = c * 32;
    int w = tid >> 6, lane = tid & 63, l15 = lane & 15, lk = lane >> 4;
    const float* din = isq ? qin : kin;
    ushort* xh = isq ? qh : kh;

    if (!isq) {
#pragma unroll
        for (int i = 0; i < 8; ++i) {
            int f = tid + 256 * i;
            int sl = f >> 6, e = f & 63;
            v_lds[sl][e] = vin[((size_t)((s0 + sl) * 8 + h) << 6) + e];
        }
    }

    // A-frags + row sum-of-squares; one wave per (mt,kt) publishes the hi tile
    s16x8 ah[2][2], al[2][2];
    float qq[2] = {0.f, 0.f};
#pragma unroll
    for (int mt = 0; mt < 2; ++mt)
#pragma unroll
        for (int kt = 0; kt < 2; ++kt) {
            size_t goff = ((size_t)((s0 + mt * 16 + l15) * 8 + h) << 6) + kt * 32 + lk * 8;
            qq[mt] += load8_split(din + goff, ah[mt][kt], al[mt][kt]);
            if (w == mt * 2 + kt)
                *(s16x8*)(xh + goff) = ah[mt][kt];
        }
    if (w == 0) {
#pragma unroll
        for (int mt = 0; mt < 2; ++mt) {
            float s = qq[mt];
            s += __shfl_xor(s, 16, 64);
            s += __shfl_xor(s, 32, 64);
            if (lk == 0) diag_lds[mt * 16 + l15] = 0.0625f * s;
        }
    }
    // dash via split-bf16 MFMA
    f32x4 dacc[2] = {{0,0,0,0},{0,0,0,0}};
#pragma unroll
    for (int kt = 0; kt < 2; ++kt) {
        s16x8 bh, bl;
        load8_split(proj + ((w * 16 + l15) << 6) + kt * 32 + lk * 8, bh, bl);
#pragma unroll
        for (int mt = 0; mt < 2; ++mt) {
            dacc[mt] = MFMA(ah[mt][kt], bh, dacc[mt]);
            dacc[mt] = MFMA(ah[mt][kt], bl, dacc[mt]);
            dacc[mt] = MFMA(al[mt][kt], bh, dacc[mt]);
        }
    }

    if (isq) {
#pragma unroll
        for (int mt = 0; mt < 2; ++mt)
#pragma unroll
            for (int j = 0; j < 4; ++j) {
                float rm = fabsf(DN * dacc[mt][j]);
#pragma unroll
                for (int m = 1; m < 16; m <<= 1) rm = fmaxf(rm, __shfl_xor(rm, m, 16));
                if (l15 == 0) ad_part[w][mt * 16 + lk * 4 + j] = rm;
            }
        __syncthreads();
        if (tid < 32) {
            float ad = fmaxf(fmaxf(ad_part[0][tid], ad_part[1][tid]),
                             fmaxf(ad_part[2][tid], ad_part[3][tid]));
            ad_lds[tid] = ad;
            qls[(size_t)((s0 + tid) * 8 + h)] = ad - diag_lds[tid];
        }
        __syncthreads();
#pragma unroll
        for (int mt = 0; mt < 2; ++mt)
#pragma unroll
            for (int j = 0; j < 4; ++j) {
                int t = mt * 16 + lk * 4 + j;
                int r = w * 16 + l15;
                float dash = DN * dacc[mt][j];
                float ad = ad_lds[t];
                p_lds[t][r]      = RATIO * __expf( dash - ad);
                p_lds[t][64 + r] = RATIO * __expf(-dash - ad);
            }
    } else {
        __syncthreads();   // diag_lds + v_lds ready
#pragma unroll
        for (int mt = 0; mt < 2; ++mt)
#pragma unroll
            for (int j = 0; j < 4; ++j) {
                int t = mt * 16 + lk * 4 + j;
                int r = w * 16 + l15;
                float dash = DN * dacc[mt][j];
                float cc = diag_lds[t] + KLS;
                p_lds[t][r]      = RATIO * __expf( dash - cc);
                p_lds[t][64 + r] = RATIO * __expf(-dash - cc);
            }
        // vT[h*64+d][s0+sidx] = v[s0+sidx][d]
#pragma unroll
        for (int j = 0; j < 8; ++j) {
            int o = tid + 256 * j;
            int d = o >> 5, sidx = o & 31;
            vT[((size_t)(h * 64 + d) << 10) + s0 + sidx] = f2bf(v_lds[sidx][d]);
        }
    }
    __syncthreads();

    // publish prime features (hi-only bf16), vectorized 16B stores
    ushort* ph = isq ? qph : kph;
#pragma unroll
    for (int i = 0; i < 2; ++i) {
        int o = tid + 256 * i;          // 0..511
        int sl = o >> 4;                // row 0..31
        int mc = (o & 15) * 8;          // col 0,8,...,120
        ushort tmp[8];
#pragma unroll
        for (int j = 0; j < 8; ++j) tmp[j] = f2bf(p_lds[sl][mc + j]);
        *(s16x8*)(ph + ((size_t)((s0 + sl) * 8 + h) << 7) + mc) = pack8(tmp);
    }
    if (!isq) {
        if (tid < 128) {
            float s = 0.f;
#pragma unroll
            for (int sl = 0; sl < 32; ++sl) s += p_lds[sl][tid];
            pksum[(h * 32 + c) * 128 + tid] = s;
        }
        s16x8 bv;
        {
            ushort tmp[8];
#pragma unroll
            for (int i = 0; i < 8; ++i) tmp[i] = f2bf(v_lds[lk * 8 + i][w * 16 + l15]);
            bv = pack8(tmp);
        }
        // pkv layout: [h][c][d][m] bf16 — u16x4 stores (m consecutive)
        ushort* pkvb = pkv + ((size_t)(h * 32 + c) << 13);
        int d = w * 16 + l15;
#pragma unroll
        for (int mt = 0; mt < 8; ++mt) {
            ushort tmp[8];
#pragma unroll
            for (int i = 0; i < 8; ++i) tmp[i] = f2bf(p_lds[lk * 8 + i][mt * 16 + l15]);
            s16x8 a = pack8(tmp);
            f32x4 acc = {0, 0, 0, 0};
            acc = MFMA(a, bv, acc);
            u16x4 pk;
#pragma unroll
            for (int j = 0; j < 4; ++j) pk[j] = f2bf(acc[j]);
            *(u16x4*)(pkvb + d * 128 + mt * 16 + lk * 4) = pk;
        }
    }
}

// ============ kvred: 512 blocks (h = bid&7, d = bid>>3); bf16 partials ========
__global__ __launch_bounds__(256) void kvred_kernel(const ushort* __restrict__ pkv,
    const float* __restrict__ pksum, ushort* __restrict__ kvT, float* __restrict__ ksum)
{
    __shared__ float buf[2][128];
    int tid = threadIdx.x;
    int h = blockIdx.x & 7, d = blockIdx.x >> 3;   // d in [0,64)
    int m = tid & 127, half = tid >> 7;
    float s = 0.f;
#pragma unroll
    for (int c = 0; c < 16; ++c) {
        int cc = half * 16 + c;
        s += bf2f(pkv[((size_t)(h * 32 + cc) << 13) + d * 128 + m]);
    }
    buf[half][m] = s;
    __syncthreads();
    if (tid < 128)
        kvT[((size_t)(h * 64 + d) << 7) + m] = f2bf(buf[0][m] + buf[1][m]);
    if (blockIdx.x < 8 && tid < 128) {       // d==0 blocks: h = blockIdx.x
        float ks = 0.f;
#pragma unroll
        for (int c = 0; c < 32; ++c) ks += pksum[(h * 32 + c) * 128 + tid];
        ksum[h * 128 + tid] = ks;
    }
}

// ============ main: 512 blocks x 256 thr, 16-row tiles, h = blockIdx&7 ==========
// Plain-bf16 QK/DP (hi-only operands): 6 MFMA + 6 B-frag loads per tile.
__global__ __launch_bounds__(256) void main_kernel(
    const ushort* __restrict__ qh, const ushort* __restrict__ qph,
    const float* __restrict__ qls,
    const ushort* __restrict__ kh, const ushort* __restrict__ kph,
    const ushort* __restrict__ vT, const ushort* __restrict__ kvT,
    const float* __restrict__ ksum, float* __restrict__ outp)
{
    __shared__ float QKb[16][152];
    __shared__ float DPb[16][152];
    __shared__ ushort ATb[16][168];
    __shared__ float qk1s[16], plss[16], lns[16], pss[16];

    int tid = threadIdx.x;
    int h = blockIdx.x & 7, t0 = (blockIdx.x >> 3) << 4;
    int w = tid >> 6, lane = tid & 63, l15 = lane & 15, lk = lane >> 4;
    int tl = tid >> 4, sub = tid & 15;

    // ---- phase 0: prefetch kv B-frags (consumed at the very end) ----
    int dcol = w * 16 + l15;
    s16x8 bkv[4];
    {
        const ushort* kvTrow = kvT + ((size_t)(h * 64 + dcol) << 7);
#pragma unroll
        for (int kt = 0; kt < 4; ++kt)
            bkv[kt] = *(const s16x8*)(kvTrow + kt * 32 + lk * 8);
    }

    // ---- A-fragments (16 q-rows, hi-only) ----
    s16x8 aqh[2], aph[4];
    {
        int tg = (t0 + l15) * 8 + h;
#pragma unroll
        for (int kt = 0; kt < 2; ++kt)
            aqh[kt] = *(const s16x8*)(qh + ((size_t)tg << 6) + kt * 32 + lk * 8);
#pragma unroll
        for (int kt = 0; kt < 4; ++kt)
            aph[kt] = *(const s16x8*)(qph + ((size_t)tg << 7) + kt * 32 + lk * 8);
    }

    // ---- row scalars qk1, pls (16 rows x 16 threads) ----
    {
        int gid = (t0 + tl) * 8 + h;
        const ushort* ph = qph + ((size_t)gid << 7) + sub * 8;
        const float* ksp = ksum + h * 128 + sub * 8;
        float s = 0.f;
#pragma unroll
        for (int i = 0; i < 8; ++i) s += bf2f(ph[i]) * ksp[i];
#pragma unroll
        for (int m = 1; m < 16; m <<= 1) s += __shfl_xor(s, m, 16);
        if (sub == 0) qk1s[tl] = s;
        if (sub == 1) plss[tl] = qls[gid] + KLS;
    }

    // ---- phase 1: QK & DP bf16 GEMMs over 9 window tiles ----
    for (int nt = w; nt < 9; nt += 4) {
        int srow = min(max(t0 - 64 + nt * 16 + l15, 0), 1023);
        size_t kbase = ((size_t)(srow * 8 + h)) << 6;
        size_t pbase = ((size_t)(srow * 8 + h)) << 7;
        s16x8 bkh[2], bph[4];
#pragma unroll
        for (int kt = 0; kt < 2; ++kt)
            bkh[kt] = *(const s16x8*)(kh + kbase + kt * 32 + lk * 8);
#pragma unroll
        for (int kt = 0; kt < 4; ++kt)
            bph[kt] = *(const s16x8*)(kph + pbase + kt * 32 + lk * 8);
        f32x4 aqk = {0,0,0,0}, adp = {0,0,0,0};
#pragma unroll
        for (int kt = 0; kt < 2; ++kt)
            aqk = MFMA(aqh[kt], bkh[kt], aqk);
#pragma unroll
        for (int kt = 0; kt < 4; ++kt)
            adp = MFMA(aph[kt], bph[kt], adp);
#pragma unroll
        for (int r = 0; r < 4; ++r) {
            int row = lk * 4 + r, cs = nt * 16 + l15;
            QKb[row][cs] = TEMP * aqk[r];
            DPb[row][cs] = adp[r];
        }
    }
    __syncthreads();

    // ---- phase 1.5: row stats -> log_norm, prime_scale ----
    int clo = max(tl, 64 - t0);
    int chi = min(tl + 128, 1088 - t0);
    float mx = -1e30f, dsum = 0.f;
#pragma unroll
    for (int kk = 0; kk < 9; ++kk) {
        int cs = sub + 16 * kk;
        if (cs >= clo && cs < chi) {
            mx = fmaxf(mx, QKb[tl][cs]);
            dsum += DPb[tl][cs];
        }
    }
#pragma unroll
    for (int m = 1; m < 16; m <<= 1) {
        mx = fmaxf(mx, __shfl_xor(mx, m, 16));
        dsum += __shfl_xor(dsum, m, 16);
    }
    float se = 0.f;
#pragma unroll
    for (int kk = 0; kk < 9; ++kk) {
        int cs = sub + 16 * kk;
        if (cs >= clo && cs < chi) se += __expf(QKb[tl][cs] - mx);
    }
#pragma unroll
    for (int m = 1; m < 16; m <<= 1) se += __shfl_xor(se, m, 16);
    if (sub == 0) {
        float lse = mx + __logf(se);
        float lr = __logf(fmaxf(qk1s[tl] - dsum, 1e-24f)) + plss[tl];
        float mab = fmaxf(lse, lr);
        float ln = mab + log1pf(__expf(fminf(lse, lr) - mab));
        lns[tl] = ln;
        pss[tl] = __expf(plss[tl] - ln);
    }
    __syncthreads();

    // ---- phase 2a: attn_local -> bf16 s-aligned buffer (zeros outside window) ----
    {
        float ln = lns[tl], ps = pss[tl];
#pragma unroll
        for (int kk = 0; kk < 10; ++kk) {
            int cs = sub + 16 * kk;
            float att = 0.f;
            if (kk < 9 && cs >= clo && cs < chi)
                att = __expf(QKb[tl][cs] - ln) - DPb[tl][cs] * ps;
            ATb[tl][cs] = f2bf(att);
        }
    }
    __syncthreads();

    // ---- phase 2b: out = attn_sb @ V + ps * (q' @ kv) ----
    f32x4 acc1 = {0,0,0,0}, acc2 = {0,0,0,0};
    const ushort* vTrow = vT + ((size_t)(h * 64 + dcol) << 10);
#pragma unroll
    for (int kt = 0; kt < 5; ++kt) {
        s16x8 a = *(const s16x8*)&ATb[l15][kt * 32 + lk * 8];
        int sc = t0 - 64 + kt * 32 + lk * 8;
        sc = min(max(sc, 0), 1016);
        s16x8 b = *(const s16x8*)(vTrow + sc);
        acc1 = MFMA(a, b, acc1);
    }
#pragma unroll
    for (int kt = 0; kt < 4; ++kt)
        acc2 = MFMA(aph[kt], bkv[kt], acc2);
#pragma unroll
    for (int r = 0; r < 4; ++r) {
        int row = lk * 4 + r;
        float val = acc1[r] + pss[row] * acc2[r];
        outp[((size_t)((t0 + row) * 8 + h) << 6) + dcol] = val;
    }
}

extern "C" void kernel_launch(void* const* d_in, const int* in_sizes, int n_in,
                              void* d_out, int out_size, void* d_ws, size_t ws_size,
                              hipStream_t stream) {
    const float* q    = (const float*)d_in[0];
    const float* kk   = (const float*)d_in[1];
    const float* vv   = (const float*)d_in[2];
    const float* proj = (const float*)d_in[3];
    float* out = (float*)d_out;
    float* ws  = (float*)d_ws;

    ushort* qh    = (ushort*)(ws);             // 8192*64 bf16 (262144 f32 slots)
    ushort* qph   = (ushort*)(ws + 262144);    // 8192*128 bf16 (524288)
    float*  qls   = ws + 786432;               // 8192
    ushort* kh    = (ushort*)(ws + 794624);    // 262144
    ushort* kph   = (ushort*)(ws + 1056768);   // 524288
    ushort* vT    = (ushort*)(ws + 1581056);   // 8*64*1024 bf16 (262144)
    ushort* kvT   = (ushort*)(ws + 1843200);   // 8*64*128 bf16 (32768)
    float*  ksum  = ws + 1875968;              // 1024
    float*  pksum = ws + 1876992;              // 32768
    ushort* pkv   = (ushort*)(ws + 1909760);   // 8*32*64*128 bf16 (1048576) -> ends 2958336

    feat_kernel<<<512, 256, 0, stream>>>(q, kk, vv, proj, qh, qph, qls,
                                         kh, kph, vT, pkv, pksum);
    kvred_kernel<<<512, 256, 0, stream>>>(pkv, pksum, kvT, ksum);
    main_kernel<<<512, 256, 0, stream>>>(qh, qph, qls, kh, kph,
                                         vT, kvT, ksum, out);
}